// Round 9
// baseline (58.288 us; speedup 1.0000x reference)
//
#include <hip/hip_runtime.h>
#include <hip/hip_bf16.h>
#include <math.h>

// SimpleMemoryBank: B=8,T=4096,D=512,SLOTS=128,TOPK=8
#define R_TOTAL 32768
#define DM      512
#define NSLOT   128
#define KSEL    8

typedef _Float16 half8 __attribute__((ext_vector_type(8)));
typedef float    floatx4 __attribute__((ext_vector_type(4)));

// ---------------- prep: split K into f16 hi/lo AND pre-swizzle into chunk-major staged
// layout Ks[c][u][slot][8] (u=0..3 hi-planes kg, u=4..7 lo-planes kg). Each chunk's
// 16 KB contiguous -> main kernel's global_load_lds is lane-coalesced (R8 win).
__global__ void smb_prepK(const float* __restrict__ Km, _Float16* __restrict__ Ks) {
  const int i = blockIdx.x * 256 + threadIdx.x;   // 65536 = slot*512 + d
  const int slot = i >> 9;
  const int d    = i & 511;
  const float f  = Km[i] * 256.0f;                // exact (power of 2)
  const _Float16 h  = (_Float16)f;
  const _Float16 lo = (_Float16)(f - (float)h);   // exact residual (Sterbenz)
  const int c  = d >> 5;          // chunk 0..15
  const int kg = (d >> 3) & 3;    // plane-within-chunk 0..3
  const int j  = d & 7;
  Ks[((((c * 8) + kg    ) * NSLOT + slot) << 3) + j] = h;    // hi plane u=kg
  Ks[((((c * 8) + 4 + kg) * NSLOT + slot) << 3) + j] = lo;   // lo plane u=4+kg
}

// async 16B global->LDS (width literal 16; LDS dest = wave-uniform base + lane*16)
__device__ __forceinline__ void load16_lds(const _Float16* g, _Float16* l) {
  __builtin_amdgcn_global_load_lds(
      (const __attribute__((address_space(1))) unsigned int*)g,
      (__attribute__((address_space(3))) unsigned int*)l, 16, 0, 0);
}

// ---------------- fused main ---------------------------------------------------------------
// 512-thread blocks, 8 waves = 4 row-groups x 2 slot-halves; 64 rows/block, grid 512.
// K-loop barriers use COUNTED vmcnt (T4): __syncthreads would drain vmcnt(0), killing the
// distance-2 q prefetch every chunk (R8's residual ~15-25us stall). Per iter the 2 newest
// outstanding vmem ops are q(c+2) -> s_waitcnt vmcnt(2) forces stage(c+1) complete while
// q flies across the barrier. lgkmcnt(0) preserves the read-before-DMA-rewrite ordering
// __syncthreads used to give (stage[cb] is rewritten one barrier after its reads).
__global__ __launch_bounds__(512, 4) void smb_main(
    const float* __restrict__ q,     // [R_TOTAL, DM]
    const _Float16* __restrict__ Ks, // [16][8][NSLOT][8] staged chunk-major split-K
    const float* __restrict__ Vm,    // [NSLOT, DM]
    const float* __restrict__ sal,   // [NSLOT]
    float* __restrict__ outv,        // [R_TOTAL, DM]
    float* __restrict__ outw)        // [R_TOTAL, KSEL]
{
  __shared__ _Float16 stage[2][8][NSLOT][8];
  __shared__ float slab[64][132];     // block-wide score slab

  const int t  = threadIdx.x;
  const int w  = t >> 6;          // wave 0..7
  const int l  = t & 63;          // lane
  const int li = l & 15;          // M-row / B-col within fragment
  const int kg = l >> 4;          // k-group 0..3
  const int rg = w >> 1;          // row group 0..3
  const int sh = w & 1;           // slot half 0..1
  const int r0b = blockIdx.x * 64;
  const int r0w = r0b + rg * 16;  // this wave's 16 q rows

  const float* qrow = q + (size_t)(r0w + li) * DM + kg * 8;

  floatx4 acc[4];
#pragma unroll
  for (int g = 0; g < 4; ++g) acc[g] = (floatx4){0.f, 0.f, 0.f, 0.f};

  // ---- prologue: stage(0), q(0), q(1). FIFO: [S0,S0,Q0,Q0,Q1,Q1] -> vmcnt(4) = S0 done ----
#pragma unroll
  for (int p = 0; p < 2; ++p) {
    const _Float16* src = Ks + ((((size_t)0 * 8 + w) * NSLOT + p * 64 + l) << 3);
    load16_lds(src, &stage[0][w][p * 64 + l][0]);
  }
  float4 q0c = *(const float4*)(qrow + 0);
  float4 q1c = *(const float4*)(qrow + 4);
  float4 q0n = *(const float4*)(qrow + 32);
  float4 q1n = *(const float4*)(qrow + 36);
  __builtin_amdgcn_sched_barrier(0);
  asm volatile("s_waitcnt vmcnt(4)" ::: "memory");
  __builtin_amdgcn_s_barrier();
  __builtin_amdgcn_sched_barrier(0);

  // ---- main loop: stage(c+1) + q(c+2) issued BEFORE compute(c); counted-vmcnt barrier ----
#pragma unroll 2
  for (int c = 0; c < 16; ++c) {
    const int cb = c & 1, nb = cb ^ 1;
    float4 q0nn, q1nn;
    if (c < 15) {
#pragma unroll
      for (int p = 0; p < 2; ++p) {
        const _Float16* src = Ks + ((((size_t)(c + 1) * 8 + w) * NSLOT + p * 64 + l) << 3);
        load16_lds(src, &stage[nb][w][p * 64 + l][0]);
      }
    }
    if (c < 14) {
      q0nn = *(const float4*)(qrow + (c + 2) * 32);
      q1nn = *(const float4*)(qrow + (c + 2) * 32 + 4);
    }

    // compute chunk c: fragments from LDS, f16-split MFMA (3 terms, ~1e-8 rel exact)
    half8 a1, a2;
#pragma unroll
    for (int j = 0; j < 4; ++j) {
      const float f0 = q0c[j] * 16.0f;   // exact scale
      const float f1 = q1c[j] * 16.0f;
      const _Float16 h0 = (_Float16)f0;
      const _Float16 h1 = (_Float16)f1;
      a1[j]     = h0;  a2[j]     = (_Float16)(f0 - (float)h0);
      a1[4 + j] = h1;  a2[4 + j] = (_Float16)(f1 - (float)h1);
    }
#pragma unroll
    for (int g = 0; g < 4; ++g) {
      const int slot = sh * 64 + g * 16 + li;
      const half8 b1 = *(const half8*)&stage[cb][kg][slot][0];
      const half8 b2 = *(const half8*)&stage[cb][4 + kg][slot][0];
      acc[g] = __builtin_amdgcn_mfma_f32_16x16x32_f16(a1, b1, acc[g], 0, 0, 0);
      acc[g] = __builtin_amdgcn_mfma_f32_16x16x32_f16(a2, b1, acc[g], 0, 0, 0);
      acc[g] = __builtin_amdgcn_mfma_f32_16x16x32_f16(a1, b2, acc[g], 0, 0, 0);
    }
    q0c = q0n; q1c = q1n;
    if (c < 14) { q0n = q0nn; q1n = q1nn; }

    if (c < 14) {
      // FIFO at barrier: [Q(c+1)?,Q(c+1)?, S(c+1),S(c+1), Q(c+2),Q(c+2)]
      // vmcnt(2): newest 2 (q prefetches) may fly; stage(c+1) forced complete.
      __builtin_amdgcn_sched_barrier(0);
      asm volatile("s_waitcnt vmcnt(2) lgkmcnt(0)" ::: "memory");
      __builtin_amdgcn_s_barrier();
      __builtin_amdgcn_sched_barrier(0);
    } else if (c == 14) {
      // newest ops are S(15) themselves -> must drain fully.
      __builtin_amdgcn_sched_barrier(0);
      asm volatile("s_waitcnt vmcnt(0) lgkmcnt(0)" ::: "memory");
      __builtin_amdgcn_s_barrier();
      __builtin_amdgcn_sched_barrier(0);
    }
    // c == 15: no trailing barrier (epilogue writes slab, disjoint from stage)
  }

  // ---- epilogue: scores = (acc/4096)/sqrt(D) + salience -> block slab ----
  // D-frag layout (m89-verified): col = lane&15 (slot), row = (lane>>4)*4 + reg (q row)
  const float den = sqrtf((float)DM);
#pragma unroll
  for (int g = 0; g < 4; ++g) {
    const int col = sh * 64 + g * 16 + li;
    const float sv = sal[col];
#pragma unroll
    for (int i = 0; i < 4; ++i) {
      const float s = (acc[g][i] * 0.000244140625f) / den + sv;  // *2^-12 exact, IEEE div
      slab[rg * 16 + kg * 4 + i][col] = s;
    }
  }
  __syncthreads();   // slab written by both slot-half waves; full drain fine here

  // ---- Phase B: per-row top-8 (tie: lower index) + softmax. 8 lanes/row. ----
  const int row = t >> 3;   // 0..63
  const int lq  = t & 7;

  float bs[8]; int bi[8];
#pragma unroll
  for (int p = 0; p < 8; ++p) { bs[p] = -3.0e38f; bi[p] = 0x7fffffff; }

#pragma unroll
  for (int jj = 0; jj < 16; ++jj) {
    const int   j = jj * 8 + lq;
    const float s = slab[row][j];
    bool c[8];
#pragma unroll
    for (int p = 0; p < 8; ++p) c[p] = s > bs[p];   // strict > keeps earlier index on ties
    float nb[8]; int ni[8];
    nb[0] = c[0] ? s : bs[0];
    ni[0] = c[0] ? j : bi[0];
#pragma unroll
    for (int p = 7; p >= 1; --p) {
      nb[p] = c[p] ? (c[p - 1] ? bs[p - 1] : s) : bs[p];
      ni[p] = c[p] ? (c[p - 1] ? bi[p - 1] : j) : bi[p];
    }
#pragma unroll
    for (int p = 0; p < 8; ++p) { bs[p] = nb[p]; bi[p] = ni[p]; }
  }

  // merge 8 sorted lists via oct butterflies (score desc, index asc) + pop
  float ts[8]; int ti_[8];
#pragma unroll
  for (int r = 0; r < 8; ++r) {
    float hs = bs[0]; int hi = bi[0];
#pragma unroll
    for (int m = 1; m <= 4; m <<= 1) {
      const float os = __shfl_xor(hs, m, 64);
      const int   oi = __shfl_xor(hi, m, 64);
      if (os > hs || (os == hs && oi < hi)) { hs = os; hi = oi; }
    }
    ts[r] = hs; ti_[r] = hi;
    if (bs[0] == hs && bi[0] == hi) {   // winner lane pops its head (static shift)
#pragma unroll
      for (int p = 0; p < 7; ++p) { bs[p] = bs[p + 1]; bi[p] = bi[p + 1]; }
      bs[7] = -3.0e38f; bi[7] = 0x7fffffff;
    }
  }

  // softmax over the 8 selected scores; all 8 lanes hold the result redundantly
  float tw[8];
  const float mx = ts[0];
  float esum = 0.0f;
#pragma unroll
  for (int r = 0; r < 8; ++r) { tw[r] = expf(ts[r] - mx); esum += tw[r]; }
#pragma unroll
  for (int r = 0; r < 8; ++r) tw[r] /= esum;

  if (lq == 0) {
#pragma unroll
    for (int r = 0; r < 8; ++r) outw[(size_t)(r0b + row) * KSEL + r] = tw[r];
  }

  // ---- Phase C: read_vectors = sum_k w_k * V[idx_k]; top-k state already in registers ----
  const float4* __restrict__ V4 = (const float4*)Vm;
  float4* __restrict__ O4 = (float4*)outv;
  const size_t obase = (size_t)(r0b + row) * (DM / 4);
#pragma unroll 4
  for (int cc = 0; cc < 16; ++cc) {
    const int cdx = cc * 8 + lq;    // 8 lanes cover 128B contiguous per step
    float4 a; a.x = a.y = a.z = a.w = 0.0f;
#pragma unroll
    for (int r = 0; r < 8; ++r) {   // k ascending, matches reference einsum order
      const float4 v = V4[(size_t)ti_[r] * (DM / 4) + cdx];
      a.x = fmaf(tw[r], v.x, a.x);
      a.y = fmaf(tw[r], v.y, a.y);
      a.z = fmaf(tw[r], v.z, a.z);
      a.w = fmaf(tw[r], v.w, a.w);
    }
    O4[obase + cdx] = a;
  }
}

extern "C" void kernel_launch(void* const* d_in, const int* in_sizes, int n_in,
                              void* d_out, int out_size, void* d_ws, size_t ws_size,
                              hipStream_t stream) {
  const float* q   = (const float*)d_in[0];
  const float* Km  = (const float*)d_in[1];
  const float* Vm  = (const float*)d_in[2];
  const float* sal = (const float*)d_in[3];
  // d_in[4] = topk (fixed 8)

  float* outv = (float*)d_out;
  float* outw = outv + (size_t)R_TOTAL * DM;

  _Float16* Ks = (_Float16*)d_ws;   // 256 KB staged chunk-major split-K

  hipLaunchKernelGGL(smb_prepK, dim3((NSLOT * DM) / 256), dim3(256), 0, stream, Km, Ks);
  hipLaunchKernelGGL(smb_main, dim3(R_TOTAL / 64), dim3(512), 0, stream,
                     q, Ks, Vm, sal, outv, outw);
}